// Round 1
// baseline (370.791 us; speedup 1.0000x reference)
//
#include <hip/hip_runtime.h>

#define IN_F 4096
#define OUT_F 4096
#define M_DIM 8192  // 4 * 2048

typedef __attribute__((ext_vector_type(8))) short bf16x8;
typedef __attribute__((ext_vector_type(4))) float f32x4;
typedef unsigned short u16;

typedef const __attribute__((address_space(1))) void* gas_t;
typedef __attribute__((address_space(3))) void* las_t;

__device__ __forceinline__ void async16(const void* g, void* s) {
  // global -> LDS direct, 16B per lane; LDS dest = wave-uniform base + lane*16
  __builtin_amdgcn_global_load_lds((gas_t)g, (las_t)s, 16, 0, 0);
}

__device__ __forceinline__ u16 f2bf(float f) {  // RNE f32 -> bf16 bits
  union { float f; unsigned u; } v; v.f = f;
  unsigned r = v.u + 0x7FFFu + ((v.u >> 16) & 1u);
  return (u16)(r >> 16);
}

__device__ __forceinline__ u16 i2bf(int x) {  // exact for 0..255
  union { float f; unsigned u; } v; v.f = (float)x;
  return (u16)(v.u >> 16);
}

// Thread i expands codes[2i],[2i+1] -> 8 bf16 weights (16B store)
__global__ void k_decompress(const int* __restrict__ codes,
                             const int* __restrict__ table,
                             u16* __restrict__ W) {
  int i = blockIdx.x * 256 + threadIdx.x;
  int2 c = *(const int2*)(codes + (size_t)i * 2);
  int4 t0 = *(const int4*)(table + (size_t)c.x * 4);
  int4 t1 = *(const int4*)(table + (size_t)c.y * 4);
  bf16x8 o;
  o[0] = (short)i2bf(t0.x); o[1] = (short)i2bf(t0.y);
  o[2] = (short)i2bf(t0.z); o[3] = (short)i2bf(t0.w);
  o[4] = (short)i2bf(t1.x); o[5] = (short)i2bf(t1.y);
  o[6] = (short)i2bf(t1.z); o[7] = (short)i2bf(t1.w);
  *(bf16x8*)(W + (size_t)i * 8) = o;
}

// Thread i converts 8 f32 -> 8 bf16
__global__ void k_convert(const float* __restrict__ x, u16* __restrict__ xb) {
  int i = blockIdx.x * 256 + threadIdx.x;
  float4 a = *(const float4*)(x + (size_t)i * 8);
  float4 b = *(const float4*)(x + (size_t)i * 8 + 4);
  bf16x8 o;
  o[0] = (short)f2bf(a.x); o[1] = (short)f2bf(a.y);
  o[2] = (short)f2bf(a.z); o[3] = (short)f2bf(a.w);
  o[4] = (short)f2bf(b.x); o[5] = (short)f2bf(b.y);
  o[6] = (short)f2bf(b.z); o[7] = (short)f2bf(b.w);
  *(bf16x8*)(xb + (size_t)i * 8) = o;
}

// C[m][n] = sum_k Xb[m][k]*W[n][k] + bias[n]; 128x128 tile, BK=32, 4 waves
__global__ __launch_bounds__(256) void k_gemm(const u16* __restrict__ Xb,
                                              const u16* __restrict__ W,
                                              const float* __restrict__ bias,
                                              float* __restrict__ out) {
  constexpr int BK = 32;
  __shared__ u16 sA[128 * BK];  // [128 rows][32 k] row-major
  __shared__ u16 sB[128 * BK];
  const int tid = threadIdx.x;
  const int wv = tid >> 6, ln = tid & 63;
  const int bm0 = blockIdx.y * 128, bn0 = blockIdx.x * 128;
  const int wr = wv >> 1, wc = wv & 1;

  // staging: chunk c = rows [c*16, c*16+16), lane l -> row c*16+l/4, col (l&3)*8
  const int ca = wv * 2;
  const int srow = ln >> 2;
  const int scol = (ln & 3) * 8;
  const u16* gA = Xb + (size_t)(bm0 + ca * 16 + srow) * IN_F + scol;
  const u16* gB = W + (size_t)(bn0 + ca * 16 + srow) * IN_F + scol;
  u16* lA = sA + ca * 512;  // wave-uniform LDS base (1KB chunk)
  u16* lB = sB + ca * 512;

  f32x4 acc[4][4] = {};
  const int fr = ln & 15;        // A row / B col within fragment
  const int fk = (ln >> 4) * 8;  // k offset within fragment

  for (int kt = 0; kt < IN_F; kt += BK) {
    async16(gA + kt, lA);
    async16(gA + kt + 16 * IN_F, lA + 512);
    async16(gB + kt, lB);
    async16(gB + kt + 16 * IN_F, lB + 512);
    __syncthreads();  // drains vmcnt -> tiles visible

    bf16x8 af[4], bfr[4];
#pragma unroll
    for (int i = 0; i < 4; ++i) {
      af[i] = *(const bf16x8*)(sA + (wr * 64 + i * 16 + fr) * BK + fk);
      bfr[i] = *(const bf16x8*)(sB + (wc * 64 + i * 16 + fr) * BK + fk);
    }
#pragma unroll
    for (int i = 0; i < 4; ++i)
#pragma unroll
      for (int j = 0; j < 4; ++j)
        acc[i][j] = __builtin_amdgcn_mfma_f32_16x16x32_bf16(af[i], bfr[j],
                                                            acc[i][j], 0, 0, 0);
    __syncthreads();  // protect LDS before next stage
  }

  // C/D layout (m89): col = lane&15, row = (lane>>4)*4 + reg
  const int cl = ln & 15, rl = (ln >> 4) * 4;
#pragma unroll
  for (int j = 0; j < 4; ++j) {
    const int col = bn0 + wc * 64 + j * 16 + cl;
    const float bv = bias[col];
#pragma unroll
    for (int i = 0; i < 4; ++i) {
      const int row = bm0 + wr * 64 + i * 16 + rl;
      float* op = out + (size_t)row * OUT_F + col;
#pragma unroll
      for (int r = 0; r < 4; ++r) op[(size_t)r * OUT_F] = acc[i][j][r] + bv;
    }
  }
}

// Fallback (only if ws too small): one thread per output element
__global__ void k_naive(const float* __restrict__ x, const int* __restrict__ table,
                        const int* __restrict__ codes, const float* __restrict__ bias,
                        float* __restrict__ out) {
  __shared__ float sx[IN_F];
  const int m = blockIdx.y;
  const int n = blockIdx.x * 256 + threadIdx.x;
  for (int k = threadIdx.x; k < IN_F; k += 256) sx[k] = x[(size_t)m * IN_F + k];
  __syncthreads();
  float s = 0.f;
  const int* cr = codes + (size_t)n * (IN_F / 4);
  for (int k4 = 0; k4 < IN_F / 4; ++k4) {
    int code = cr[k4];
    int4 t = *(const int4*)(table + (size_t)code * 4);
    const float* xp = sx + k4 * 4;
    s += xp[0] * t.x + xp[1] * t.y + xp[2] * t.z + xp[3] * t.w;
  }
  out[(size_t)m * OUT_F + n] = s + bias[n];
}

extern "C" void kernel_launch(void* const* d_in, const int* in_sizes, int n_in,
                              void* d_out, int out_size, void* d_ws, size_t ws_size,
                              hipStream_t stream) {
  const float* x = (const float*)d_in[0];
  const int* table = (const int*)d_in[1];
  const int* codes = (const int*)d_in[2];
  const float* bias = (const float*)d_in[3];
  float* out = (float*)d_out;

  const size_t wbytes = (size_t)OUT_F * IN_F * 2;  // 33.5 MB
  const size_t xbytes = (size_t)M_DIM * IN_F * 2;  // 67 MB
  if (ws_size >= wbytes + xbytes) {
    u16* W = (u16*)d_ws;
    u16* Xb = (u16*)((char*)d_ws + wbytes);
    k_decompress<<<(OUT_F * IN_F / 4 / 2) / 256, 256, 0, stream>>>(codes, table, W);
    k_convert<<<(M_DIM * IN_F / 8) / 256, 256, 0, stream>>>(x, Xb);
    dim3 grid(OUT_F / 128, M_DIM / 128);
    k_gemm<<<grid, 256, 0, stream>>>(Xb, W, bias, out);
  } else {
    dim3 grid(OUT_F / 256, M_DIM);
    k_naive<<<grid, 256, 0, stream>>>(x, table, codes, bias, out);
  }
}

// Round 2
// 283.273 us; speedup vs baseline: 1.3090x; 1.3090x over previous
//
#include <hip/hip_runtime.h>

#define IN_F 4096
#define OUT_F 4096
#define M_DIM 8192  // 4 * 2048
#define NT 64       // K tiles of 64

typedef __attribute__((ext_vector_type(8))) short bf16x8;
typedef __attribute__((ext_vector_type(4))) float f32x4;
typedef unsigned short u16;

typedef const __attribute__((address_space(1))) void* gas_t;
typedef __attribute__((address_space(3))) void* las_t;

__device__ __forceinline__ void async16(const void* g, void* s) {
  // global -> LDS direct; LDS dest = wave-uniform base + lane*16
  __builtin_amdgcn_global_load_lds((gas_t)g, (las_t)s, 16, 0, 0);
}

__device__ __forceinline__ u16 f2bf(float f) {  // RNE f32 -> bf16 bits
  union { float f; unsigned u; } v; v.f = f;
  unsigned r = v.u + 0x7FFFu + ((v.u >> 16) & 1u);
  return (u16)(r >> 16);
}

__device__ __forceinline__ u16 i2bf(int x) {  // exact for 0..255
  union { float f; unsigned u; } v; v.f = (float)x;
  return (u16)(v.u >> 16);
}

__global__ void k_decompress(const int* __restrict__ codes,
                             const int* __restrict__ table,
                             u16* __restrict__ W) {
  int i = blockIdx.x * 256 + threadIdx.x;
  int2 c = *(const int2*)(codes + (size_t)i * 2);
  int4 t0 = *(const int4*)(table + (size_t)c.x * 4);
  int4 t1 = *(const int4*)(table + (size_t)c.y * 4);
  bf16x8 o;
  o[0] = (short)i2bf(t0.x); o[1] = (short)i2bf(t0.y);
  o[2] = (short)i2bf(t0.z); o[3] = (short)i2bf(t0.w);
  o[4] = (short)i2bf(t1.x); o[5] = (short)i2bf(t1.y);
  o[6] = (short)i2bf(t1.z); o[7] = (short)i2bf(t1.w);
  *(bf16x8*)(W + (size_t)i * 8) = o;
}

__global__ void k_convert(const float* __restrict__ x, u16* __restrict__ xb) {
  int i = blockIdx.x * 256 + threadIdx.x;
  float4 a = *(const float4*)(x + (size_t)i * 8);
  float4 b = *(const float4*)(x + (size_t)i * 8 + 4);
  bf16x8 o;
  o[0] = (short)f2bf(a.x); o[1] = (short)f2bf(a.y);
  o[2] = (short)f2bf(a.z); o[3] = (short)f2bf(a.w);
  o[4] = (short)f2bf(b.x); o[5] = (short)f2bf(b.y);
  o[6] = (short)f2bf(b.z); o[7] = (short)f2bf(b.w);
  *(bf16x8*)(xb + (size_t)i * 8) = o;
}

#define BAR()    asm volatile("s_barrier" ::: "memory")
#define WAITV6() asm volatile("s_waitcnt vmcnt(6)" ::: "memory")
#define WAITV0() asm volatile("s_waitcnt vmcnt(0)" ::: "memory")
#define WAITL0() asm volatile("s_waitcnt lgkmcnt(0)" ::: "memory")
#define WAITL8() asm volatile("s_waitcnt lgkmcnt(8)" ::: "memory")
#define MFMA(va, vb, vc) __builtin_amdgcn_mfma_f32_16x16x32_bf16((va), (vb), (vc), 0, 0, 0)

// 256x256 tile, BK=64, 8 waves (2Mx4N), 8-phase counted-vmcnt schedule.
// LDS: A[2 dbuf][2 half][128][64]u16 at 0, B same at 65536 -> 128 KiB.
// Swizzle: byte_col ^= (row&7)<<4 (involution, 16B blocks) — applied on
// the READ address and on the gload_lds global SOURCE (dest stays linear).
__global__ __launch_bounds__(512, 2) void k_gemm256(
    const u16* __restrict__ Xb, const u16* __restrict__ W,
    const float* __restrict__ bias, float* __restrict__ out) {
  extern __shared__ char sm[];
  const int tid = threadIdx.x;
  const int w = tid >> 6, ln = tid & 63;
  const int wr = w >> 2, wc = w & 3;  // 2 x 4 waves

  // XCD-aware swizzle: 512 wgs = 8 xcds * 64-chunks (bijective, 512%8==0)
  const int orig = blockIdx.x;
  const int wg = (orig & 7) * 64 + (orig >> 3);
  const int bm0 = (wg >> 4) * 256;  // 32 M-blocks
  const int bn0 = (wg & 15) * 256;  // 16 N-blocks

  // staging source geometry (pre-swizzled so linear LDS dest holds swizzled data)
  const int srow = ln >> 3;                 // 0..7
  const int scol = ((ln & 7) ^ srow) * 8;   // u16 units
  const u16* pA = Xb + (size_t)(bm0 + w * 16 + srow) * IN_F + scol;
  const u16* pB = W + (size_t)(bn0 + w * 16 + srow) * IN_F + scol;
  const int wso = w * 2048;  // wave's 2KB slot in a 16KB half

  // fragment-read bases (physical = logical col ^ ((row&7)<<4); row&7 == ln&7)
  const int l15 = ln & 15;
  const int cc0 = ((ln >> 4) * 16) ^ ((ln & 7) << 4);         // kk=0
  const int cc1 = (64 + (ln >> 4) * 16) ^ ((ln & 7) << 4);    // kk=1
  const int arA0 = (wr * 64 + l15) * 128 + cc0;               // + mq*16384 + am*2048
  const int arA1 = (wr * 64 + l15) * 128 + cc1;
  const int brB0 = 65536 + (wc * 32 + l15) * 128 + cc0;       // + nq*16384 + bn*2048
  const int brB1 = 65536 + (wc * 32 + l15) * 128 + cc1;

#define STA(t, h, db)                                                          \
  do {                                                                         \
    async16(pA + (size_t)(t)*64 + (h)*128 * IN_F,                              \
            sm + (db)*32768 + (h)*16384 + wso);                                \
    async16(pA + (size_t)(t)*64 + (h)*128 * IN_F + 8 * IN_F,                   \
            sm + (db)*32768 + (h)*16384 + wso + 1024);                         \
  } while (0)
#define STB(t, h, db)                                                          \
  do {                                                                         \
    async16(pB + (size_t)(t)*64 + (h)*128 * IN_F,                              \
            sm + 65536 + (db)*32768 + (h)*16384 + wso);                        \
    async16(pB + (size_t)(t)*64 + (h)*128 * IN_F + 8 * IN_F,                   \
            sm + 65536 + (db)*32768 + (h)*16384 + wso + 1024);                 \
  } while (0)

  // prologue: tile0 fully + tile1 {Ah0,Bh0,Bh1}; 3 half-tiles stay in flight
  STA(0, 0, 0); STB(0, 0, 0); STB(0, 1, 0); STA(0, 1, 0);
  STA(1, 0, 1); STB(1, 0, 1); STB(1, 1, 1);
  f32x4 acc[8][4] = {};
  bf16x8 a[4][2], b0[2][2], b1[2][2];
  WAITV6();
  BAR();

  for (int t = 0; t < NT; ++t) {
    const int d = t & 1, dn = d ^ 1;
    const int d32 = d * 32768;
    // ---- phase 1 (mq0,nq0): read A(d,h0)+B(d,h0); stage (t+1)A h1 -> dn
#pragma unroll
    for (int am = 0; am < 4; ++am) {
      a[am][0] = *(const bf16x8*)(sm + d32 + arA0 + am * 2048);
      a[am][1] = *(const bf16x8*)(sm + d32 + arA1 + am * 2048);
    }
#pragma unroll
    for (int bn = 0; bn < 2; ++bn) {
      b0[bn][0] = *(const bf16x8*)(sm + d32 + brB0 + bn * 2048);
      b0[bn][1] = *(const bf16x8*)(sm + d32 + brB1 + bn * 2048);
    }
    if (t + 1 < NT) STA(t + 1, 1, dn);
    WAITL8();
    BAR();
    WAITL0();
    __builtin_amdgcn_sched_barrier(0);
    __builtin_amdgcn_s_setprio(1);
#pragma unroll
    for (int am = 0; am < 4; ++am)
#pragma unroll
      for (int bn = 0; bn < 2; ++bn) {
        acc[am][bn] = MFMA(a[am][0], b0[bn][0], acc[am][bn]);
        acc[am][bn] = MFMA(a[am][1], b0[bn][1], acc[am][bn]);
      }
    __builtin_amdgcn_s_setprio(0);
    BAR();
    // ---- phase 2 (mq0,nq1): read B(d,h1); stage (t+2)A h0 -> d
#pragma unroll
    for (int bn = 0; bn < 2; ++bn) {
      b1[bn][0] = *(const bf16x8*)(sm + d32 + 16384 + brB0 + bn * 2048);
      b1[bn][1] = *(const bf16x8*)(sm + d32 + 16384 + brB1 + bn * 2048);
    }
    if (t + 2 < NT) STA(t + 2, 0, d);
    BAR();
    WAITL0();
    __builtin_amdgcn_sched_barrier(0);
    __builtin_amdgcn_s_setprio(1);
#pragma unroll
    for (int am = 0; am < 4; ++am)
#pragma unroll
      for (int bn = 0; bn < 2; ++bn) {
        acc[am][2 + bn] = MFMA(a[am][0], b1[bn][0], acc[am][2 + bn]);
        acc[am][2 + bn] = MFMA(a[am][1], b1[bn][1], acc[am][2 + bn]);
      }
    __builtin_amdgcn_s_setprio(0);
    BAR();
    // ---- phase 3 (mq1,nq1): read A(d,h1); stage (t+2)B h0 -> d
#pragma unroll
    for (int am = 0; am < 4; ++am) {
      a[am][0] = *(const bf16x8*)(sm + d32 + 16384 + arA0 + am * 2048);
      a[am][1] = *(const bf16x8*)(sm + d32 + 16384 + arA1 + am * 2048);
    }
    if (t + 2 < NT) STB(t + 2, 0, d);
    BAR();
    WAITL0();
    __builtin_amdgcn_sched_barrier(0);
    __builtin_amdgcn_s_setprio(1);
#pragma unroll
    for (int am = 0; am < 4; ++am)
#pragma unroll
      for (int bn = 0; bn < 2; ++bn) {
        acc[4 + am][2 + bn] = MFMA(a[am][0], b1[bn][0], acc[4 + am][2 + bn]);
        acc[4 + am][2 + bn] = MFMA(a[am][1], b1[bn][1], acc[4 + am][2 + bn]);
      }
    __builtin_amdgcn_s_setprio(0);
    BAR();
    // ---- phase 4 (mq1,nq0): no reads; stage (t+2)B h1 -> d; counted vmcnt
    if (t + 2 < NT) STB(t + 2, 1, d);
    BAR();
    __builtin_amdgcn_s_setprio(1);
#pragma unroll
    for (int am = 0; am < 4; ++am)
#pragma unroll
      for (int bn = 0; bn < 2; ++bn) {
        acc[4 + am][bn] = MFMA(a[am][0], b0[bn][0], acc[4 + am][bn]);
        acc[4 + am][bn] = MFMA(a[am][1], b0[bn][1], acc[4 + am][bn]);
      }
    __builtin_amdgcn_s_setprio(0);
    if (t < NT - 2) { WAITV6(); } else { WAITV0(); }
    BAR();
  }

  // epilogue: C/D layout col=ln&15, row=(ln>>4)*4+reg; bias fused
  const int r4 = (ln >> 4) * 4;
#pragma unroll
  for (int in = 0; in < 4; ++in) {
    const int nq = in >> 1, bn = in & 1;
    const int col = bn0 + nq * 128 + wc * 32 + bn * 16 + l15;
    const float bv = bias[col];
#pragma unroll
    for (int im = 0; im < 8; ++im) {
      const int mq = im >> 2, am = im & 3;
      const int row = bm0 + mq * 128 + wr * 64 + am * 16 + r4;
      float* op = out + (size_t)row * OUT_F + col;
#pragma unroll
      for (int r = 0; r < 4; ++r) op[(size_t)r * OUT_F] = acc[im][in][r] + bv;
    }
  }
#undef STA
#undef STB
}

// Fallback: one thread per output element
__global__ void k_naive(const float* __restrict__ x, const int* __restrict__ table,
                        const int* __restrict__ codes, const float* __restrict__ bias,
                        float* __restrict__ out) {
  __shared__ float sx[IN_F];
  const int m = blockIdx.y;
  const int n = blockIdx.x * 256 + threadIdx.x;
  for (int k = threadIdx.x; k < IN_F; k += 256) sx[k] = x[(size_t)m * IN_F + k];
  __syncthreads();
  float s = 0.f;
  const int* cr = codes + (size_t)n * (IN_F / 4);
  for (int k4 = 0; k4 < IN_F / 4; ++k4) {
    int code = cr[k4];
    int4 t = *(const int4*)(table + (size_t)code * 4);
    const float* xp = sx + k4 * 4;
    s += xp[0] * t.x + xp[1] * t.y + xp[2] * t.z + xp[3] * t.w;
  }
  out[(size_t)m * OUT_F + n] = s + bias[n];
}

extern "C" void kernel_launch(void* const* d_in, const int* in_sizes, int n_in,
                              void* d_out, int out_size, void* d_ws, size_t ws_size,
                              hipStream_t stream) {
  const float* x = (const float*)d_in[0];
  const int* table = (const int*)d_in[1];
  const int* codes = (const int*)d_in[2];
  const float* bias = (const float*)d_in[3];
  float* out = (float*)d_out;

  const size_t wbytes = (size_t)OUT_F * IN_F * 2;
  const size_t xbytes = (size_t)M_DIM * IN_F * 2;
  if (ws_size >= wbytes + xbytes) {
    u16* W = (u16*)d_ws;
    u16* Xb = (u16*)((char*)d_ws + wbytes);
    k_decompress<<<(OUT_F * IN_F / 4 / 2) / 256, 256, 0, stream>>>(codes, table, W);
    k_convert<<<(M_DIM * IN_F / 8) / 256, 256, 0, stream>>>(x, Xb);
    (void)hipFuncSetAttribute((const void*)k_gemm256,
                              hipFuncAttributeMaxDynamicSharedMemorySize, 131072);
    k_gemm256<<<dim3((M_DIM / 256) * (OUT_F / 256)), dim3(512), 131072, stream>>>(
        Xb, W, bias, out);
  } else {
    dim3 grid(OUT_F / 256, M_DIM);
    k_naive<<<grid, 256, 0, stream>>>(x, table, codes, bias, out);
  }
}